// Round 6
// baseline (616.192 us; speedup 1.0000x reference)
//
#include <hip/hip_runtime.h>
#include <math.h>

#define EM_EPS 1e-8f
#define BN_SC 0.999995000037f   // 1/sqrt(1+1e-5)
#define LOG2PI 1.8378770664093453f

// ---------------- conv1 (5x5 s2 VALID) + bn1 ----------------
// x (32,3,32,32), w (256,3,5,5) -> out (32,256,14,14)
__global__ __launch_bounds__(256) void k_conv1(
    const float* __restrict__ x, const float* __restrict__ w,
    const float* __restrict__ g, const float* __restrict__ bb,
    float* __restrict__ out) {
  int idx = blockIdx.x * 256 + threadIdx.x;
  int ox = idx % 14; int t = idx / 14;
  int oy = t % 14; t /= 14;
  int co = t % 256; int b = t / 256;
  const float* xb = x + b * 3 * 1024;
  const float* wc = w + co * 75;
  float acc = 0.f;
  #pragma unroll
  for (int ci = 0; ci < 3; ++ci) {
    const float* xc = xb + ci * 1024 + (oy * 2) * 32 + ox * 2;
    const float* wk = wc + ci * 25;
    #pragma unroll
    for (int kh = 0; kh < 5; ++kh)
      #pragma unroll
      for (int kw = 0; kw < 5; ++kw)
        acc = fmaf(xc[kh * 32 + kw], wk[kh * 5 + kw], acc);
  }
  out[idx] = acc * (g[co] * BN_SC) + bb[co];
}

// ------------- conv2 partial (K-split over 4 blocks) -------------
__global__ __launch_bounds__(192) void k_conv2_part(
    const float* __restrict__ in,
    const float* __restrict__ wa, const float* __restrict__ wp,
    float* __restrict__ partial) {
  __shared__ float s_in[16 * 14 * 16];   // [ci][iy][ix pad16]
  __shared__ float s_w[16 * 9 * 34];     // [ci][tap][co pad34]

  const int t   = threadIdx.x;
  const int row = t >> 4;
  const int cg  = t & 15;
  const int b   = blockIdx.x / 36;
  const int r36 = blockIdx.x % 36;
  const int gco = (r36 >> 2) * 32;
  const int kc  = r36 & 3;
  const float* inb = in + b * 50176;

  float acc[2][12];
  #pragma unroll
  for (int u = 0; u < 2; ++u)
    #pragma unroll
    for (int px = 0; px < 12; ++px) acc[u][px] = 0.f;

  for (int ch = kc * 4; ch < kc * 4 + 4; ++ch) {
    __syncthreads();
    for (int idx = t; idx < 3136; idx += 192) {
      int ci = idx / 196, r = idx - ci * 196;
      int iy = r / 14, ix = r - iy * 14;
      s_in[ci * 224 + iy * 16 + ix] = inb[ch * 3136 + idx];
    }
    for (int idx = t; idx < 4608; idx += 192) {
      int co = idx / 144, rem = idx - co * 144;
      int c = gco + co;
      float val = 0.f;
      if (c < 272) {
        const float* wrow = (c < 16) ? (wa + c * 2304) : (wp + (c - 16) * 2304);
        val = wrow[ch * 144 + rem];
      }
      s_w[rem * 34 + co] = val;
    }
    __syncthreads();

    for (int ci = 0; ci < 16; ++ci) {
      float rin[3][16];
      #pragma unroll
      for (int kh = 0; kh < 3; ++kh) {
        const float4* rp = (const float4*)&s_in[ci * 224 + (row + kh) * 16];
        #pragma unroll
        for (int x = 0; x < 4; ++x)
          *(float4*)&rin[kh][x * 4] = rp[x];
      }
      #pragma unroll
      for (int kh = 0; kh < 3; ++kh) {
        #pragma unroll
        for (int kw = 0; kw < 3; ++kw) {
          float2 wv = *(const float2*)&s_w[(ci * 9 + kh * 3 + kw) * 34 + cg * 2];
          #pragma unroll
          for (int px = 0; px < 12; ++px) {
            float iv = rin[kh][px + kw];
            acc[0][px] = fmaf(iv, wv.x, acc[0][px]);
            acc[1][px] = fmaf(iv, wv.y, acc[1][px]);
          }
        }
      }
    }
  }

  #pragma unroll
  for (int u = 0; u < 2; ++u) {
    int c = gco + cg * 2 + u;
    float* dst = partial + ((size_t)(kc * 32 + b) * 288 + c) * 144 + row * 12;
    #pragma unroll
    for (int px = 0; px < 12; ++px) dst[px] = acc[u][px];
  }
}

// ------------- conv2 reduce: sum 4 partials + bn (+sigmoid for a) -------------
__global__ __launch_bounds__(256) void k_conv2_red(
    const float* __restrict__ partial,
    const float* __restrict__ ga, const float* __restrict__ bba,
    const float* __restrict__ gp, const float* __restrict__ bbp,
    float* __restrict__ a1, float* __restrict__ pose1) {
  int idx = blockIdx.x * 256 + threadIdx.x;
  if (idx >= 32 * 272 * 144) return;
  int px = idx % 144; int r = idx / 144;
  int c = r % 272; int b = r / 272;
  const size_t base = ((size_t)b * 288 + c) * 144 + px;
  const size_t kstr = (size_t)32 * 288 * 144;
  float s = partial[base] + partial[base + kstr]
          + partial[base + 2 * kstr] + partial[base + 3 * kstr];
  if (c < 16) {
    float v = s * (ga[c] * BN_SC) + bba[c];
    a1[((size_t)b * 16 + c) * 144 + px] = 1.f / (1.f + expf(-v));
  } else {
    int cp = c - 16;
    pose1[((size_t)b * 256 + cp) * 144 + px] = s * (gp[cp] * BN_SC) + bbp[cp];
  }
}

// ------------- conv2 single-pass fallback (ws too small) -------------
__global__ __launch_bounds__(192) void k_conv2(
    const float* __restrict__ in,
    const float* __restrict__ wa, const float* __restrict__ wp,
    const float* __restrict__ ga, const float* __restrict__ bba,
    const float* __restrict__ gp, const float* __restrict__ bbp,
    float* __restrict__ a1, float* __restrict__ pose1) {
  __shared__ float s_in[16 * 14 * 16];
  __shared__ float s_w[16 * 9 * 34];

  const int t   = threadIdx.x;
  const int row = t >> 4;
  const int cg  = t & 15;
  const int b   = blockIdx.x / 9;
  const int gco = (blockIdx.x % 9) * 32;
  const float* inb = in + b * 50176;

  float acc[2][12];
  #pragma unroll
  for (int u = 0; u < 2; ++u)
    #pragma unroll
    for (int px = 0; px < 12; ++px) acc[u][px] = 0.f;

  for (int ch = 0; ch < 16; ++ch) {
    __syncthreads();
    for (int idx = t; idx < 3136; idx += 192) {
      int ci = idx / 196, r = idx - ci * 196;
      int iy = r / 14, ix = r - iy * 14;
      s_in[ci * 224 + iy * 16 + ix] = inb[ch * 3136 + idx];
    }
    for (int idx = t; idx < 4608; idx += 192) {
      int co = idx / 144, rem = idx - co * 144;
      int c = gco + co;
      float val = 0.f;
      if (c < 272) {
        const float* wrow = (c < 16) ? (wa + c * 2304) : (wp + (c - 16) * 2304);
        val = wrow[ch * 144 + rem];
      }
      s_w[rem * 34 + co] = val;
    }
    __syncthreads();

    for (int ci = 0; ci < 16; ++ci) {
      float rin[3][16];
      #pragma unroll
      for (int kh = 0; kh < 3; ++kh) {
        const float4* rp = (const float4*)&s_in[ci * 224 + (row + kh) * 16];
        #pragma unroll
        for (int x = 0; x < 4; ++x)
          *(float4*)&rin[kh][x * 4] = rp[x];
      }
      #pragma unroll
      for (int kh = 0; kh < 3; ++kh) {
        #pragma unroll
        for (int kw = 0; kw < 3; ++kw) {
          float2 wv = *(const float2*)&s_w[(ci * 9 + kh * 3 + kw) * 34 + cg * 2];
          #pragma unroll
          for (int px = 0; px < 12; ++px) {
            float iv = rin[kh][px + kw];
            acc[0][px] = fmaf(iv, wv.x, acc[0][px]);
            acc[1][px] = fmaf(iv, wv.y, acc[1][px]);
          }
        }
      }
    }
  }

  #pragma unroll
  for (int u = 0; u < 2; ++u) {
    int c = gco + cg * 2 + u;
    if (c >= 272) continue;
    if (c < 16) {
      float g_ = ga[c] * BN_SC, b_ = bba[c];
      float* dst = a1 + ((b * 16 + c) * 12 + row) * 12;
      #pragma unroll
      for (int px = 0; px < 12; ++px) {
        float v = acc[u][px] * g_ + b_;
        dst[px] = 1.f / (1.f + expf(-v));
      }
    } else {
      int cp = c - 16;
      float g_ = gp[cp] * BN_SC, b_ = bbp[cp];
      float* dst = pose1 + ((b * 256 + cp) * 12 + row) * 12;
      #pragma unroll
      for (int px = 0; px < 12; ++px)
        dst[px] = acc[u][px] * g_ + b_;
    }
  }
}

// ---------------- EM routing: block = one (b, output pixel) ----------------
// 256 threads = 4 waves; wave w owns k in [w*KKA/4, (w+1)*KKA/4).
// lane = x*16 + j. Batch-4 k-processing for ILP on the shuffle chains.
// Softmax uses per-iteration prior factor E_j = exp(L0_j+loga_j - M):
//   r_kj = E_j*exp(-s_kj) / sum_j  (no per-k max chain).
template<int K, int S, int P, int HIN, int WIN, int OH, int OW, int B>
__global__ __launch_bounds__(256, 4) void k_routing(
    const float* __restrict__ ag,      // (b,16,HIN,WIN)
    const float* __restrict__ poseg,   // (b,256,HIN,WIN)
    const float* __restrict__ Wg,      // (KKA,B,4,4)
    const float* __restrict__ bu, const float* __restrict__ ba,
    const float* __restrict__ bng, const float* __restrict__ bnb,
    float* __restrict__ aout_g,        // (b,B,OH,OW)
    float* __restrict__ pose_out_g) {  // (b,B*16,OH,OW) or null
  constexpr int A = 16;
  constexpr int KK = K * K;
  constexpr int KKA = KK * A;
  constexpr int NW = 4;
  constexpr int KPW = KKA / NW;       // 36 or 64
  constexpr int KB = 4;
  static_assert(KPW % KB == 0, "KPW%KB");

  __shared__ __attribute__((aligned(16))) float s_pp[KKA * 16];
  __shared__ float s_ain[KKA];
  __shared__ float4 sU1[NW][64];
  __shared__ float4 sU2[NW][64];
  __shared__ float  sRS[NW][64];

  const int t  = threadIdx.x;
  const int wv = t >> 6;
  const int ln = t & 63;
  const int x  = ln >> 4;
  const int j  = ln & 15;
  const int jc = (j < B) ? j : 0;
  const bool jvalid = (j < B);

  const int bi = blockIdx.x;
  const int b  = bi / (OH * OW);
  const int l  = bi % (OH * OW);
  const int oy = l / OW, ox = l % OW;

  for (int idx = t; idx < KKA * 16; idx += 256) {
    int k = idx >> 4, pe = idx & 15;
    int acap = k & 15, kki = k >> 4;
    int kh = kki / K, kw = kki % K;
    int iy = oy * S - P + kh, ix = ox * S - P + kw;
    float val = 0.f;
    if (iy >= 0 && iy < HIN && ix >= 0 && ix < WIN) {
      int c = acap * 16 + pe;
      val = poseg[((b * 256 + c) * HIN + iy) * WIN + ix];
      if (bng) val = val * (bng[c] * BN_SC) + bnb[c];
    }
    s_pp[idx] = val;
  }
  for (int k = t; k < KKA; k += 256) {
    int acap = k & 15, kki = k >> 4;
    int kh = kki / K, kw = kki % K;
    int iy = oy * S - P + kh, ix = ox * S - P + kw;
    float val = 0.f;
    if (iy >= 0 && iy < HIN && ix >= 0 && ix < WIN)
      val = ag[((b * A + acap) * HIN + iy) * WIN + ix];
    s_ain[k] = val;
  }
  __syncthreads();

  const float bu_j = bu[jc];
  const float ba_j = ba[jc];
  const int k0 = wv * KPW;

  float mu[4] = {0, 0, 0, 0}, i2s[4] = {0, 0, 0, 0};
  float Ej = 0.f;

  float p95 = 0.95f;
  for (int it = 0; it < 3; ++it) {
    const float lam = 0.01f * (1.0f - p95);
    p95 *= 0.95f;
    float U1[4] = {0, 0, 0, 0}, U2[4] = {0, 0, 0, 0}, RS = 0.f;

    for (int g = 0; g < KPW; g += KB) {
      float vv[KB][4], ain[KB], ra[KB];
      #pragma unroll
      for (int u = 0; u < KB; ++u) {
        const int k = k0 + g + u;
        const float4 pp4 = *(const float4*)&s_pp[k * 16 + x * 4];
        const float4* wr = (const float4*)(Wg + (size_t)(k * B + jc) * 16);
        const float4 w0 = wr[0], w1 = wr[1], w2 = wr[2], w3 = wr[3];
        vv[u][0] = pp4.x * w0.x + pp4.y * w1.x + pp4.z * w2.x + pp4.w * w3.x;
        vv[u][1] = pp4.x * w0.y + pp4.y * w1.y + pp4.z * w2.y + pp4.w * w3.y;
        vv[u][2] = pp4.x * w0.z + pp4.y * w1.z + pp4.z * w2.z + pp4.w * w3.z;
        vv[u][3] = pp4.x * w0.w + pp4.y * w1.w + pp4.z * w2.w + pp4.w * w3.w;
        ain[u] = s_ain[k];
      }
      if (it == 0) {
        #pragma unroll
        for (int u = 0; u < KB; ++u) ra[u] = ain[u] * (1.0f / (float)B);
      } else {
        float ss[KB], ee[KB], sm[KB];
        #pragma unroll
        for (int u = 0; u < KB; ++u) {
          float d0 = vv[u][0] - mu[0], d1 = vv[u][1] - mu[1];
          float d2 = vv[u][2] - mu[2], d3 = vv[u][3] - mu[3];
          ss[u] = d0 * d0 * i2s[0] + d1 * d1 * i2s[1]
                + d2 * d2 * i2s[2] + d3 * d3 * i2s[3];
        }
        // interleaved chains: sum over p (xor16,32), then softmax-sum over j
        #pragma unroll
        for (int u = 0; u < KB; ++u) ss[u] += __shfl_xor(ss[u], 16);
        #pragma unroll
        for (int u = 0; u < KB; ++u) ss[u] += __shfl_xor(ss[u], 32);
        #pragma unroll
        for (int u = 0; u < KB; ++u) ee[u] = Ej * __expf(-ss[u]);
        #pragma unroll
        for (int u = 0; u < KB; ++u) sm[u] = ee[u] + __shfl_xor(ee[u], 1);
        #pragma unroll
        for (int u = 0; u < KB; ++u) sm[u] += __shfl_xor(sm[u], 2);
        #pragma unroll
        for (int u = 0; u < KB; ++u) sm[u] += __shfl_xor(sm[u], 4);
        #pragma unroll
        for (int u = 0; u < KB; ++u) sm[u] += __shfl_xor(sm[u], 8);
        #pragma unroll
        for (int u = 0; u < KB; ++u)
          ra[u] = ee[u] * __builtin_amdgcn_rcpf(sm[u] + 1e-30f) * ain[u];
      }
      #pragma unroll
      for (int u = 0; u < KB; ++u) {
        RS += ra[u];
        float t0 = ra[u] * vv[u][0], t1 = ra[u] * vv[u][1];
        float t2 = ra[u] * vv[u][2], t3 = ra[u] * vv[u][3];
        U1[0] += t0; U1[1] += t1; U1[2] += t2; U1[3] += t3;
        U2[0] += t0 * vv[u][0]; U2[1] += t1 * vv[u][1];
        U2[2] += t2 * vv[u][2]; U2[3] += t3 * vv[u][3];
      }
    }

    // ---- cross-wave reduction over the 4 k-partitions ----
    sU1[wv][ln] = make_float4(U1[0], U1[1], U1[2], U1[3]);
    sU2[wv][ln] = make_float4(U2[0], U2[1], U2[2], U2[3]);
    sRS[wv][ln] = RS;
    __syncthreads();
    float fU1[4] = {0, 0, 0, 0}, fU2[4] = {0, 0, 0, 0}, fRS = 0.f;
    #pragma unroll
    for (int w2 = 0; w2 < NW; ++w2) {
      float4 a = sU1[w2][ln];
      float4 c = sU2[w2][ln];
      fU1[0] += a.x; fU1[1] += a.y; fU1[2] += a.z; fU1[3] += a.w;
      fU2[0] += c.x; fU2[1] += c.y; fU2[2] += c.z; fU2[3] += c.w;
      fRS    += sRS[w2][ln];
    }
    __syncthreads();   // protect partials before next iteration's writes

    // ---- stats (redundant in every wave; lane (x,j) owns p = x*4+z) ----
    const float inv = 1.f / (fRS + EM_EPS);
    const float Cc  = fRS * inv;
    float lsum_p = 0.f;
    #pragma unroll
    for (int z = 0; z < 4; ++z) {
      mu[z] = fU1[z] * inv;
      float s2 = fU2[z] * inv - mu[z] * mu[z] * (2.f - Cc);
      s2 = fmaxf(s2, 0.f) + EM_EPS;
      i2s[z] = 0.5f / s2;
      lsum_p += __logf(s2);
    }
    float cap  = 4.f * bu_j + 0.5f * lsum_p;
    float lsum = lsum_p;
    cap += __shfl_xor(cap, 16); lsum += __shfl_xor(lsum, 16);
    cap += __shfl_xor(cap, 32); lsum += __shfl_xor(lsum, 32);
    const float cost = cap * fRS;
    const float aout = 1.f / (1.f + __expf(-(lam * (ba_j - cost))));
    const float L0   = -0.5f * (16.f * LOG2PI + lsum);
    const float loga = __logf(aout + EM_EPS);

    // per-iteration prior factor for next E-step (masked max over valid j)
    const float lj = L0 + loga;
    float mj = jvalid ? lj : -1e30f;
    mj = fmaxf(mj, __shfl_xor(mj, 1));
    mj = fmaxf(mj, __shfl_xor(mj, 2));
    mj = fmaxf(mj, __shfl_xor(mj, 4));
    mj = fmaxf(mj, __shfl_xor(mj, 8));
    Ej = jvalid ? __expf(lj - mj) : 0.f;

    if (it == 2 && wv == 0 && jvalid) {
      if (x == 0) aout_g[((b * B + j) * OH + oy) * OW + ox] = aout;
      if (pose_out_g) {
        #pragma unroll
        for (int z = 0; z < 4; ++z)
          pose_out_g[((b * (B * 16) + j * 16 + x * 4 + z) * OH + oy) * OW + ox] = mu[z];
      }
    }
  }
}

// ---------------- spatial mean ----------------
__global__ __launch_bounds__(64) void k_mean(const float* __restrict__ a4,
                                             float* __restrict__ out) {
  int idx = blockIdx.x * 64 + threadIdx.x;
  if (idx >= 320) return;
  const float* pa = a4 + idx * 25;
  float s = 0.f;
  #pragma unroll
  for (int i = 0; i < 25; ++i) s += pa[i];
  out[idx] = s * (1.f / 25.f);
}

extern "C" void kernel_launch(void* const* d_in, const int* in_sizes, int n_in,
                              void* d_out, int out_size, void* d_ws, size_t ws_size,
                              hipStream_t stream) {
  const float* x       = (const float*)d_in[0];
  const float* conv1_w = (const float*)d_in[1];
  const float* bn1_g   = (const float*)d_in[2];
  const float* bn1_b   = (const float*)d_in[3];
  const float* conva_w = (const float*)d_in[4];
  const float* bna_g   = (const float*)d_in[5];
  const float* bna_b   = (const float*)d_in[6];
  const float* convp_w = (const float*)d_in[7];
  const float* bnp_g   = (const float*)d_in[8];
  const float* bnp_b   = (const float*)d_in[9];
  const float* W1      = (const float*)d_in[10];
  const float* bu1     = (const float*)d_in[11];
  const float* ba1     = (const float*)d_in[12];
  const float* bnc1_g  = (const float*)d_in[13];
  const float* bnc1_b  = (const float*)d_in[14];
  const float* W2      = (const float*)d_in[15];
  const float* bu2     = (const float*)d_in[16];
  const float* ba2     = (const float*)d_in[17];
  const float* bnc2_g  = (const float*)d_in[18];
  const float* bnc2_b  = (const float*)d_in[19];
  const float* Wfc     = (const float*)d_in[20];
  const float* bufc    = (const float*)d_in[21];
  const float* bafc    = (const float*)d_in[22];

  float* ws    = (float*)d_ws;
  float* out1  = ws;                          // 32*256*14*14 = 1605632
  float* a1    = out1  + 32 * 256 * 14 * 14;  // 73728
  float* pose1 = a1    + 32 * 16 * 12 * 12;   // 1179648
  float* a2    = pose1 + 32 * 256 * 12 * 12;  // 18432
  float* pose2 = a2    + 32 * 16 * 6 * 6;     // 294912
  float* a3    = pose2 + 32 * 256 * 6 * 6;    // 18432
  float* pose3 = a3    + 32 * 16 * 6 * 6;     // 294912
  float* a4    = pose3 + 32 * 256 * 6 * 6;    // 8000
  float* partial = a4  + 8000;                // 4*32*288*144 = 5308416
  const size_t base_floats = 3493696;
  const size_t need = (base_floats + (size_t)4 * 32 * 288 * 144) * 4;

  k_conv1<<<6272, 256, 0, stream>>>(x, conv1_w, bn1_g, bn1_b, out1);
  if (ws_size >= need) {
    k_conv2_part<<<1152, 192, 0, stream>>>(out1, conva_w, convp_w, partial);
    k_conv2_red<<<4896, 256, 0, stream>>>(partial, bna_g, bna_b, bnp_g, bnp_b,
                                          a1, pose1);
  } else {
    k_conv2<<<288, 192, 0, stream>>>(out1, conva_w, convp_w, bna_g, bna_b,
                                     bnp_g, bnp_b, a1, pose1);
  }
  k_routing<3, 2, 1, 12, 12, 6, 6, 16><<<32 * 36, 256, 0, stream>>>(
      a1, pose1, W1, bu1, ba1, nullptr, nullptr, a2, pose2);
  k_routing<3, 1, 1, 6, 6, 6, 6, 16><<<32 * 36, 256, 0, stream>>>(
      a2, pose2, W2, bu2, ba2, bnc1_g, bnc1_b, a3, pose3);
  k_routing<4, 1, 1, 6, 6, 5, 5, 10><<<32 * 25, 256, 0, stream>>>(
      a3, pose3, Wfc, bufc, bafc, bnc2_g, bnc2_b, a4, nullptr);
  k_mean<<<5, 64, 0, stream>>>(a4, (float*)d_out);
}